// Round 6
// baseline (1651.642 us; speedup 1.0000x reference)
//
#include <hip/hip_runtime.h>
#include <math.h>
#include <stdint.h>

#define NBATCH 2
#define NPTS 50000
#define NSP  4000
#define NC   24                 // cells per axis
#define NCL  (NC * NC * NC)     // 13824 linear cells (spoint CSR)
#define NCM  32768              // morton cell space for point sorting (32^3)
#define CELL 0.35f
#define INVC (1.0f / CELL)
#define ORG  4.2f               // grid covers [-4.2, 4.2)
#define BIG  3.4e38f

#define MED3(a,b,c) __builtin_amdgcn_fmed3f((a),(b),(c))

__device__ __forceinline__ int cellc(float x) {
    int c = (int)floorf((x + ORG) * INVC);
    return min(max(c, 0), NC - 1);
}
__device__ __forceinline__ unsigned spread3(unsigned x) {
    x &= 0x3ff;
    x = (x | (x << 16)) & 0x030000FFu;
    x = (x | (x << 8))  & 0x0300F00Fu;
    x = (x | (x << 4))  & 0x030C30C3u;
    x = (x | (x << 2))  & 0x09249249u;
    return x;
}

// ---------------- preprocessing ----------------

__global__ void bin_kernel(const float* __restrict__ pts, const float* __restrict__ spts,
                           int* __restrict__ sp_cnt, int* __restrict__ pt_cnt) {
    const int t = blockIdx.x * 256 + threadIdx.x;
    if (t < NBATCH * NSP) {
        const int b = t / NSP, j = t - b * NSP;
        const float* s = spts + ((size_t)b * NSP + j) * 3;
        const int cc = (cellc(s[2]) * NC + cellc(s[1])) * NC + cellc(s[0]);
        atomicAdd(&sp_cnt[b * NCL + cc], 1);
    } else if (t < NBATCH * NSP + NBATCH * NPTS) {
        const int u = t - NBATCH * NSP;
        const int b = u / NPTS, i = u - b * NPTS;
        const float* p = pts + ((size_t)b * NPTS + i) * 3;
        const unsigned m = spread3(cellc(p[0])) | (spread3(cellc(p[1])) << 1)
                         | (spread3(cellc(p[2])) << 2);
        atomicAdd(&pt_cnt[b * NCM + m], 1);
    }
}

__global__ void prefix_kernel(int* __restrict__ sp_cnt, int* __restrict__ sp_start,
                              int* __restrict__ sp_cur,
                              int* __restrict__ pt_cnt, int* __restrict__ pt_start,
                              int* __restrict__ pt_cur) {
    const bool ispt = blockIdx.x >= 2;
    const int b = blockIdx.x & 1;
    const int n = ispt ? NCM : NCL;
    int* cnt = (ispt ? pt_cnt : sp_cnt) + b * n;
    int* st  = (ispt ? pt_start : sp_start) + b * (n + 1);
    int* cu  = (ispt ? pt_cur : sp_cur) + b * n;
    __shared__ int wsum[16], wpre[16], stot;
    const int lane = threadIdx.x & 63, wid = threadIdx.x >> 6;
    int carry = 0;
    for (int base = 0; base < n; base += 1024) {
        const int i = base + (int)threadIdx.x;
        const int v = (i < n) ? cnt[i] : 0;
        int s = v;
#pragma unroll
        for (int o = 1; o < 64; o <<= 1) { int t2 = __shfl_up(s, o); if (lane >= o) s += t2; }
        if (lane == 63) wsum[wid] = s;
        __syncthreads();
        if (threadIdx.x == 0) {
            int a = 0;
            for (int w = 0; w < 16; ++w) { wpre[w] = a; a += wsum[w]; }
            stot = a;
        }
        __syncthreads();
        const int exc = carry + wpre[wid] + s - v;
        if (i < n) { st[i] = exc; cu[i] = exc; }
        carry += stot;
        __syncthreads();
    }
    if (threadIdx.x == 0) st[n] = carry;
}

__global__ void scatter_kernel(const float* __restrict__ pts, const float* __restrict__ spts,
                               int* __restrict__ sp_cur, int* __restrict__ pt_cur,
                               float4* __restrict__ ssp, int* __restrict__ perm) {
    const int t = blockIdx.x * 256 + threadIdx.x;
    if (t < NBATCH * NSP) {
        const int b = t / NSP, j = t - b * NSP;
        const float* s = spts + ((size_t)b * NSP + j) * 3;
        const float x = s[0], y = s[1], z = s[2];
        const int cc = (cellc(z) * NC + cellc(y)) * NC + cellc(x);
        const int pos = atomicAdd(&sp_cur[b * NCL + cc], 1);
        ssp[b * NSP + pos] = make_float4(x, y, z, 0.f);
    } else if (t < NBATCH * NSP + NBATCH * NPTS) {
        const int u = t - NBATCH * NSP;
        const int b = u / NPTS, i = u - b * NPTS;
        const float* p = pts + ((size_t)b * NPTS + i) * 3;
        const unsigned m = spread3(cellc(p[0])) | (spread3(cellc(p[1])) << 1)
                         | (spread3(cellc(p[2])) << 2);
        const int pos = atomicAdd(&pt_cur[b * NCM + m], 1);
        perm[b * NPTS + pos] = i;
    }
}

// ---------------- main kernel ----------------

// Scan contiguous x-chunk (this wave's quarter) of row (y,z) over [xa,xb].
template <class F>
__device__ __forceinline__ void scan_row(const int* __restrict__ st,
                                         const float4* __restrict__ ssp,
                                         int z, int y, int xa, int xb, int wv, F&& body) {
    if ((unsigned)z >= NC || (unsigned)y >= NC) return;
    xa = max(xa, 0); xb = min(xb, NC - 1);
    if (xa > xb) return;
    const int len = xb - xa + 1;
    const int qa = xa + (len * wv) / 4;
    const int qb = xa + (len * (wv + 1)) / 4 - 1;
    if (qa > qb) return;
    const int rowb = (z * NC + y) * NC;
    const int s0 = st[rowb + qa];
    const int s1 = st[rowb + qb + 1];
    for (int t = s0; t < s1; ++t) {
        const float4 s = ssp[t];
        body(s.x, s.y, s.z, t);
    }
}

// Stage k: k==1 -> whole box_1; k>=2 -> shell box_k \ box_{k-1}.
template <class F>
__device__ __forceinline__ void scan_stage(const int* __restrict__ st,
                                           const float4* __restrict__ ssp, int k,
                                           int mnx, int mxx, int mny, int mxy,
                                           int mnz, int mxz, int wv, F&& body) {
    const int xlo = mnx - k, xhi = mxx + k;
    const int ylo = mny - k, yhi = mxy + k;
    const int zlo = mnz - k, zhi = mxz + k;
    for (int z = max(zlo, 0); z <= min(zhi, NC - 1); ++z) {
        const bool zface = (z == zlo) || (z == zhi);
        for (int y = max(ylo, 0); y <= min(yhi, NC - 1); ++y) {
            const bool yface = (y == ylo) || (y == yhi);
            if (k == 1 || zface || yface) {
                scan_row(st, ssp, z, y, xlo, xhi, wv, body);
            } else {
                scan_row(st, ssp, z, y, xlo, xlo, wv, body);
                scan_row(st, ssp, z, y, xhi, xhi, 3 - wv, body);
            }
        }
    }
}

__global__ __launch_bounds__(256, 6) void voronoi_main(
    const float* __restrict__ pts,
    const int* __restrict__ sp_start,    // (NBATCH, NCL+1) CSR over sorted spoints
    const float4* __restrict__ ssp,      // (NBATCH, NSP) cell-sorted spoints
    const int* __restrict__ perm,        // (NBATCH, NPTS) morton-sorted -> orig
    float* __restrict__ out)             // (NBATCH, NPTS)
{
    __shared__ float ld [4][64][13];     // per-wave top-11 lists (pad 13)
    __shared__ float ld2[2][64][13];     // pair-merged lists
    __shared__ float lad[4][64];
    __shared__ int   lai[4][64];
    __shared__ float lbb[4][64];

    const int b    = blockIdx.y;
    const int lane = threadIdx.x & 63;
    const int wv   = __builtin_amdgcn_readfirstlane(threadIdx.x >> 6);  // force SGPR

    int sidx = blockIdx.x * 64 + lane;
    const bool valid = (sidx < NPTS);
    sidx = min(sidx, NPTS - 1);
    const int orig = perm[b * NPTS + sidx];
    const float* pp = pts + ((size_t)b * NPTS + orig) * 3;
    const float px = pp[0], py = pp[1], pz = pp[2];
    const int icx = cellc(px), icy = cellc(py), icz = cellc(pz);

    // Wave bounding box of the 64 points (identical across the 4 waves).
    int mnx = icx, mxx = icx, mny = icy, mxy = icy, mnz = icz, mxz = icz;
#pragma unroll
    for (int o = 1; o < 64; o <<= 1) {
        mnx = min(mnx, __shfl_xor(mnx, o)); mxx = max(mxx, __shfl_xor(mxx, o));
        mny = min(mny, __shfl_xor(mny, o)); mxy = max(mxy, __shfl_xor(mxy, o));
        mnz = min(mnz, __shfl_xor(mnz, o)); mxz = max(mxz, __shfl_xor(mxz, o));
    }
    mnx = __builtin_amdgcn_readfirstlane(mnx); mxx = __builtin_amdgcn_readfirstlane(mxx);
    mny = __builtin_amdgcn_readfirstlane(mny); mxy = __builtin_amdgcn_readfirstlane(mxy);
    mnz = __builtin_amdgcn_readfirstlane(mnz); mxz = __builtin_amdgcn_readfirstlane(mxz);

    const int* st = sp_start + b * (NCL + 1);
    const float4* sspb = ssp + (size_t)b * NSP;

    float d0 = BIG, d1 = BIG, d2 = BIG, d3 = BIG, d4 = BIG, d5 = BIG;
    float d6 = BIG, d7 = BIG, d8 = BIG, d9 = BIG, d10 = BIG;
    int i0 = 0;

    auto bodyA = [&](float sx, float sy, float sz, int t) {
        const float dx = px - sx, dy = py - sy, dz = pz - sz;
        const float nd = fmaf(dx, dx, fmaf(dy, dy, dz * dz));
        d10 = MED3(d9, d10, nd); d9 = MED3(d8, d9, nd); d8 = MED3(d7, d8, nd);
        d7  = MED3(d6, d7,  nd); d6 = MED3(d5, d6, nd); d5 = MED3(d4, d5, nd);
        d4  = MED3(d3, d4,  nd); d3 = MED3(d2, d3, nd); d2 = MED3(d1, d2, nd);
        d1  = MED3(d0, d1,  nd);
        i0 = (nd < d0) ? t : i0;
        d0 = fminf(d0, nd);
    };

    scan_stage(st, sspb, 1, mnx, mxx, mny, mxy, mnz, mxz, wv, bodyA);

#define INS_M(v) {                                                 \
        m10 = MED3(m9, m10, (v)); m9 = MED3(m8, m9, (v));          \
        m8  = MED3(m7, m8, (v));  m7 = MED3(m6, m7, (v));          \
        m6  = MED3(m5, m6, (v));  m5 = MED3(m4, m5, (v));          \
        m4  = MED3(m3, m4, (v));  m3 = MED3(m2, m3, (v));          \
        m2  = MED3(m1, m2, (v));  m1 = MED3(m0, m1, (v));          \
        m0  = fminf(m0, (v));                                      \
    }

    float d10g = BIG;
    int k = 1;
    for (;;) {
        // Exact union 11th across the 4 disjoint per-wave lists:
        // pair-merge (own U partner) then order-statistic across pairs.
        ld[wv][lane][0] = d0;  ld[wv][lane][1] = d1;  ld[wv][lane][2] = d2;
        ld[wv][lane][3] = d3;  ld[wv][lane][4] = d4;  ld[wv][lane][5] = d5;
        ld[wv][lane][6] = d6;  ld[wv][lane][7] = d7;  ld[wv][lane][8] = d8;
        ld[wv][lane][9] = d9;  ld[wv][lane][10] = d10;
        __syncthreads();
        float m0 = d0, m1 = d1, m2 = d2, m3 = d3, m4 = d4, m5 = d5;
        float m6 = d6, m7 = d7, m8 = d8, m9 = d9, m10 = d10;
        {
            const float* q = ld[wv ^ 1][lane];
            INS_M(q[0]); INS_M(q[1]); INS_M(q[2]); INS_M(q[3]); INS_M(q[4]);
            INS_M(q[5]); INS_M(q[6]); INS_M(q[7]); INS_M(q[8]); INS_M(q[9]);
            INS_M(q[10]);
        }
        ld2[wv >> 1][lane][0] = m0;  ld2[wv >> 1][lane][1] = m1;
        ld2[wv >> 1][lane][2] = m2;  ld2[wv >> 1][lane][3] = m3;
        ld2[wv >> 1][lane][4] = m4;  ld2[wv >> 1][lane][5] = m5;
        ld2[wv >> 1][lane][6] = m6;  ld2[wv >> 1][lane][7] = m7;
        ld2[wv >> 1][lane][8] = m8;  ld2[wv >> 1][lane][9] = m9;
        ld2[wv >> 1][lane][10] = m10;
        __syncthreads();
        {
            const float* r = ld2[(wv >> 1) ^ 1][lane];
            float g = fminf(m10, r[10]);
            g = fminf(g, fmaxf(m0, r[9])); g = fminf(g, fmaxf(m1, r[8]));
            g = fminf(g, fmaxf(m2, r[7])); g = fminf(g, fmaxf(m3, r[6]));
            g = fminf(g, fmaxf(m4, r[5])); g = fminf(g, fmaxf(m5, r[4]));
            g = fminf(g, fmaxf(m6, r[3])); g = fminf(g, fmaxf(m7, r[2]));
            g = fminf(g, fmaxf(m8, r[1])); g = fminf(g, fmaxf(m9, r[0]));
            d10g = g;
        }
        const float bnd = (float)k * CELL;
        const bool need = d10g > bnd * bnd;       // identical across waves
        if (!__any(need) || k >= NC - 1) break;
        ++k;
        __syncthreads();                          // ld/ld2 reuse fence
        scan_stage(st, sspb, k, mnx, mxx, mny, mxy, mnz, mxz, wv, bodyA);
    }

    // Global argmin (lexicographic over the 4 waves).
    lad[wv][lane] = d0; lai[wv][lane] = i0;
    __syncthreads();
    float gb = BIG; int gi = 0x7fffffff;
#pragma unroll
    for (int w = 0; w < 4; ++w) {
        const float dq = lad[w][lane];
        const int   iq = lai[w][lane];
        const bool take = (dq < gb) || (dq == gb && iq < gi);
        gb = take ? dq : gb;
        gi = take ? iq : gi;
    }
    const int i0g = gi;
    const float4 cpt = sspb[i0g];                 // per-lane gather, once
    const float ix = cpt.x, iy = cpt.y, iz = cpt.z;
    const float vx = px - ix, vy = py - iy, vz = pz - iz;
    const float d10f = d10g;
    float best = BIG;

    auto bodyB = [&](float sx, float sy, float sz, int t) {
        const float dx = px - sx, dy = py - sy, dz = pz - sz;
        const float nd = fmaf(dx, dx, fmaf(dy, dy, dz * dz));
        const bool adm = (nd <= d10f) && (t != i0g);
        const float ex = sx - ix, ey = sy - iy, ez = sz - iz;
        const float ee = fmaxf(fmaf(ex, ex, fmaf(ey, ey, ez * ez)), 1e-30f);
        const float dt = fmaf(vx, ex, fmaf(vy, ey, vz * ez));
        const float u  = fmaf(-0.5f, ee, dt);
        const float t2 = u * u * __builtin_amdgcn_rcpf(ee);
        best = adm ? fminf(best, t2) : best;
    };

    scan_stage(st, sspb, 1, mnx, mxx, mny, mxy, mnz, mxz, wv, bodyB);
    for (int kb = 1;;) {
        const float bnd = (float)kb * CELL;
        const bool need = d10f > bnd * bnd;
        if (!__any(need) || kb >= NC - 1) break;
        ++kb;
        scan_stage(st, sspb, kb, mnx, mxx, mny, mxy, mnz, mxz, wv, bodyB);
    }

    lbb[wv][lane] = best;
    __syncthreads();
    if (wv == 0) {
        const float m = fminf(fminf(lbb[0][lane], lbb[1][lane]),
                              fminf(lbb[2][lane], lbb[3][lane]));
        if (valid) out[(size_t)b * NPTS + orig] = m;
    }
}

// ---------------- launch ----------------

extern "C" void kernel_launch(void* const* d_in, const int* in_sizes, int n_in,
                              void* d_out, int out_size, void* d_ws, size_t ws_size,
                              hipStream_t stream) {
    const float* pts  = (const float*)d_in[0];   // (2, 50000, 3)
    const float* spts = (const float*)d_in[1];   // (2, 4000, 3)
    float* out = (float*)d_out;                  // (2, 50000)

    int* W = (int*)d_ws;
    int* sp_cnt   = W;                            // 2*NCL
    int* pt_cnt   = sp_cnt + 2 * NCL;             // 2*NCM
    int* sp_start = pt_cnt + 2 * NCM;             // 2*(NCL+1)
    int* sp_cur   = sp_start + 2 * (NCL + 1);     // 2*NCL
    int* pt_start = sp_cur + 2 * NCL;             // 2*(NCM+1)
    int* pt_cur   = pt_start + 2 * (NCM + 1);     // 2*NCM
    int* perm     = pt_cur + 2 * NCM;             // 2*NPTS
    float4* ssp   = (float4*)(((uintptr_t)(perm + 2 * NPTS) + 15) & ~(uintptr_t)15);

    hipMemsetAsync(W, 0, (size_t)(2 * NCL + 2 * NCM) * sizeof(int), stream);

    const int npre = (NBATCH * NSP + NBATCH * NPTS + 255) / 256;
    bin_kernel<<<npre, 256, 0, stream>>>(pts, spts, sp_cnt, pt_cnt);
    prefix_kernel<<<4, 1024, 0, stream>>>(sp_cnt, sp_start, sp_cur,
                                          pt_cnt, pt_start, pt_cur);
    scatter_kernel<<<npre, 256, 0, stream>>>(pts, spts, sp_cur, pt_cur, ssp, perm);

    dim3 grid((NPTS + 63) / 64, NBATCH);
    voronoi_main<<<grid, 256, 0, stream>>>(pts, sp_start, ssp, perm, out);
}

// Round 7
// 813.335 us; speedup vs baseline: 2.0307x; 2.0307x over previous
//
#include <hip/hip_runtime.h>
#include <math.h>
#include <stdint.h>

#define NBATCH 2
#define NPTS 50000
#define NSP  4000
#define NC   24                 // cells per axis
#define NCL  (NC * NC * NC)     // 13824 linear cells
#define CELL 0.35f
#define INVC (1.0f / CELL)
#define ORG  4.2f               // grid covers [-4.2, 4.2); 24 * 0.35 = 8.4
#define CAP  1024               // LDS candidate tile (float4)
#define BIG  3.4e38f

#define MED3(a,b,c) __builtin_amdgcn_fmed3f((a),(b),(c))

__device__ __forceinline__ int cellc(float x) {
    int c = (int)floorf((x + ORG) * INVC);
    return min(max(c, 0), NC - 1);
}

// ---------------- preprocessing ----------------

__global__ void bin_kernel(const float* __restrict__ pts, const float* __restrict__ spts,
                           int* __restrict__ sp_cnt, int* __restrict__ pt_cnt) {
    const int t = blockIdx.x * 256 + threadIdx.x;
    if (t < NBATCH * NSP) {
        const int b = t / NSP, j = t - b * NSP;
        const float* s = spts + ((size_t)b * NSP + j) * 3;
        const int cc = (cellc(s[2]) * NC + cellc(s[1])) * NC + cellc(s[0]);
        atomicAdd(&sp_cnt[b * NCL + cc], 1);
    } else if (t < NBATCH * NSP + NBATCH * NPTS) {
        const int u = t - NBATCH * NSP;
        const int b = u / NPTS, i = u - b * NPTS;
        const float* p = pts + ((size_t)b * NPTS + i) * 3;
        const int cc = (cellc(p[2]) * NC + cellc(p[1])) * NC + cellc(p[0]);
        atomicAdd(&pt_cnt[b * NCL + cc], 1);
    }
}

// 4 blocks: 0,1 -> sp_cnt b0,b1 ; 2,3 -> pt_cnt b0,b1. n = NCL each.
__global__ void prefix_kernel(int* __restrict__ sp_cnt, int* __restrict__ sp_start,
                              int* __restrict__ sp_cur,
                              int* __restrict__ pt_cnt, int* __restrict__ pt_start,
                              int* __restrict__ pt_cur) {
    const bool ispt = blockIdx.x >= 2;
    const int b = blockIdx.x & 1;
    int* cnt = (ispt ? pt_cnt : sp_cnt) + b * NCL;
    int* st  = (ispt ? pt_start : sp_start) + b * (NCL + 1);
    int* cu  = (ispt ? pt_cur : sp_cur) + b * NCL;
    __shared__ int wsum[16], wpre[16], stot;
    const int lane = threadIdx.x & 63, wid = threadIdx.x >> 6;
    int carry = 0;
    for (int base = 0; base < NCL; base += 1024) {
        const int i = base + (int)threadIdx.x;
        const int v = (i < NCL) ? cnt[i] : 0;
        int s = v;
#pragma unroll
        for (int o = 1; o < 64; o <<= 1) { int t2 = __shfl_up(s, o); if (lane >= o) s += t2; }
        if (lane == 63) wsum[wid] = s;
        __syncthreads();
        if (threadIdx.x == 0) {
            int a = 0;
            for (int w = 0; w < 16; ++w) { wpre[w] = a; a += wsum[w]; }
            stot = a;
        }
        __syncthreads();
        const int exc = carry + wpre[wid] + s - v;
        if (i < NCL) { st[i] = exc; cu[i] = exc; }
        carry += stot;
        __syncthreads();
    }
    if (threadIdx.x == 0) st[NCL] = carry;
}

__global__ void scatter_kernel(const float* __restrict__ pts, const float* __restrict__ spts,
                               int* __restrict__ sp_cur, int* __restrict__ pt_cur,
                               float4* __restrict__ ssp, int* __restrict__ perm) {
    const int t = blockIdx.x * 256 + threadIdx.x;
    if (t < NBATCH * NSP) {
        const int b = t / NSP, j = t - b * NSP;
        const float* s = spts + ((size_t)b * NSP + j) * 3;
        const float x = s[0], y = s[1], z = s[2];
        const int cc = (cellc(z) * NC + cellc(y)) * NC + cellc(x);
        const int pos = atomicAdd(&sp_cur[b * NCL + cc], 1);
        ssp[b * NSP + pos] = make_float4(x, y, z, 0.f);
    } else if (t < NBATCH * NSP + NBATCH * NPTS) {
        const int u = t - NBATCH * NSP;
        const int b = u / NPTS, i = u - b * NPTS;
        const float* p = pts + ((size_t)b * NPTS + i) * 3;
        const int cc = (cellc(p[2]) * NC + cellc(p[1])) * NC + cellc(p[0]);
        const int pos = atomicAdd(&pt_cur[b * NCL + cc], 1);
        perm[b * NPTS + pos] = i;
    }
}

// ---------------- main kernel ----------------

// Gather all cells of box_k (shell=false) or box_k \ box_{k-1} (shell=true)
// into the LDS tile (windowed, exact), scanning windows with `body`.
// All control flow block-uniform; copies/scan lane-parallel.
template <class F>
__device__ __forceinline__ void stage_scan(
    int k, bool shell,
    int mnx, int mxx, int mny, int mxy, int mnz, int mxz,
    const int* __restrict__ st, const float4* __restrict__ sspb,
    float4* __restrict__ tile, int* __restrict__ wsum,
    int tid, int lane, int wv, F&& body)
{
    const int xlo = mnx - k, ylo = mny - k, zlo = mnz - k;
    const int nx = mxx - mnx + 1 + 2 * k;
    const int ny = mxy - mny + 1 + 2 * k;
    const int nz = mxz - mnz + 1 + 2 * k;
    const int nxy = nx * ny;
    const int ncells = nxy * nz;
    int fill = 0;                       // uniform across threads
    for (int base = 0; base < ncells; base += 256) {
        const int idx = base + tid;
        int cnt = 0, src = 0;
        if (idx < ncells) {
            const int cz = idx / nxy;
            const int r  = idx - cz * nxy;
            const int cy = r / nx;
            const int cx = r - cy * nx;
            const bool skip = shell && cx >= 1 && cx <= nx - 2 &&
                              cy >= 1 && cy <= ny - 2 && cz >= 1 && cz <= nz - 2;
            const int ax = xlo + cx, ay = ylo + cy, az = zlo + cz;
            if (!skip && (unsigned)ax < NC && (unsigned)ay < NC && (unsigned)az < NC) {
                const int c = (az * NC + ay) * NC + ax;
                src = st[c];
                cnt = st[c + 1] - src;
            }
        }
        // Block-wide exclusive prefix of cnt.
        int s = cnt;
#pragma unroll
        for (int o = 1; o < 64; o <<= 1) { const int t2 = __shfl_up(s, o); if (lane >= o) s += t2; }
        if (lane == 63) wsum[wv] = s;
        __syncthreads();
        const int t0 = wsum[0], t1 = wsum[1], t2w = wsum[2], t3 = wsum[3];
        int wpre = 0;
        if (wv > 0) wpre += t0;
        if (wv > 1) wpre += t1;
        if (wv > 2) wpre += t2w;
        const int total = t0 + t1 + t2w + t3;
        __syncthreads();                // wsum reused next round

        int dst  = fill + wpre + (s - cnt);
        int rem  = cnt;
        int srcp = src;
        int newfill = fill + total;     // uniform
        while (newfill > CAP) {
            while (rem > 0 && dst < CAP) {
                const float4 v = sspb[srcp];
                tile[dst] = make_float4(v.x, v.y, v.z, __int_as_float(srcp));
                ++dst; ++srcp; --rem;
            }
            __syncthreads();
            {   // scan full tile, 4-way wave split
                const int lo = (CAP * wv) >> 2, hi = (CAP * (wv + 1)) >> 2;
                for (int i = lo; i < hi; ++i) {
                    const float4 sv = tile[i];
                    body(sv.x, sv.y, sv.z, __float_as_int(sv.w));
                }
            }
            __syncthreads();
            dst -= CAP;
            newfill -= CAP;
        }
        while (rem > 0) {
            const float4 v = sspb[srcp];
            tile[dst] = make_float4(v.x, v.y, v.z, __int_as_float(srcp));
            ++dst; ++srcp; --rem;
        }
        fill = newfill;
    }
    __syncthreads();
    if (fill > 0) {
        const int lo = (fill * wv) >> 2, hi = (fill * (wv + 1)) >> 2;
        for (int i = lo; i < hi; ++i) {
            const float4 sv = tile[i];
            body(sv.x, sv.y, sv.z, __float_as_int(sv.w));
        }
    }
    __syncthreads();
}

__global__ __launch_bounds__(256, 6) void voronoi_main(
    const float* __restrict__ pts,
    const int* __restrict__ sp_start,    // (NBATCH, NCL+1) CSR over sorted spoints
    const float4* __restrict__ ssp,      // (NBATCH, NSP) cell-sorted spoints
    const int* __restrict__ perm,        // (NBATCH, NPTS) cell-sorted -> orig
    float* __restrict__ out)             // (NBATCH, NPTS)
{
    __shared__ union U {
        float4 tile[CAP];                        // 16 KB gather tile
        struct { float ld[4][64][13]; float ld2[2][64][13]; } m;  // merge scratch
    } sh;
    __shared__ int   wsum[4];
    __shared__ float lad[4][64];
    __shared__ int   lai[4][64];
    __shared__ float lbb[4][64];

    const int tid  = threadIdx.x;
    const int lane = tid & 63;
    const int wv   = __builtin_amdgcn_readfirstlane(tid >> 6);
    const int b    = blockIdx.y;

    int sidx = blockIdx.x * 64 + lane;
    const bool valid = (sidx < NPTS);
    sidx = min(sidx, NPTS - 1);
    const int orig = perm[b * NPTS + sidx];
    const float* pp = pts + ((size_t)b * NPTS + orig) * 3;
    const float px = pp[0], py = pp[1], pz = pp[2];
    const int icx = cellc(px), icy = cellc(py), icz = cellc(pz);

    // Group bbox (identical across the 4 waves: same 64 points per lane).
    int mnx = icx, mxx = icx, mny = icy, mxy = icy, mnz = icz, mxz = icz;
#pragma unroll
    for (int o = 1; o < 64; o <<= 1) {
        mnx = min(mnx, __shfl_xor(mnx, o)); mxx = max(mxx, __shfl_xor(mxx, o));
        mny = min(mny, __shfl_xor(mny, o)); mxy = max(mxy, __shfl_xor(mxy, o));
        mnz = min(mnz, __shfl_xor(mnz, o)); mxz = max(mxz, __shfl_xor(mxz, o));
    }
    mnx = __builtin_amdgcn_readfirstlane(mnx); mxx = __builtin_amdgcn_readfirstlane(mxx);
    mny = __builtin_amdgcn_readfirstlane(mny); mxy = __builtin_amdgcn_readfirstlane(mxy);
    mnz = __builtin_amdgcn_readfirstlane(mnz); mxz = __builtin_amdgcn_readfirstlane(mxz);

    const int* st = sp_start + b * (NCL + 1);
    const float4* sspb = ssp + (size_t)b * NSP;

    float d0 = BIG, d1 = BIG, d2 = BIG, d3 = BIG, d4 = BIG, d5 = BIG;
    float d6 = BIG, d7 = BIG, d8 = BIG, d9 = BIG, d10 = BIG;
    int i0 = 0;

    auto bodyA = [&](float sx, float sy, float sz, int t) {
        const float dx = px - sx, dy = py - sy, dz = pz - sz;
        const float nd = fmaf(dx, dx, fmaf(dy, dy, dz * dz));
        d10 = MED3(d9, d10, nd); d9 = MED3(d8, d9, nd); d8 = MED3(d7, d8, nd);
        d7  = MED3(d6, d7,  nd); d6 = MED3(d5, d6, nd); d5 = MED3(d4, d5, nd);
        d4  = MED3(d3, d4,  nd); d3 = MED3(d2, d3, nd); d2 = MED3(d1, d2, nd);
        d1  = MED3(d0, d1,  nd);
        i0 = (nd < d0) ? t : i0;
        d0 = fminf(d0, nd);
    };

#define INS_M(v) {                                                 \
        m10 = MED3(m9, m10, (v)); m9 = MED3(m8, m9, (v));          \
        m8  = MED3(m7, m8, (v));  m7 = MED3(m6, m7, (v));          \
        m6  = MED3(m5, m6, (v));  m5 = MED3(m4, m5, (v));          \
        m4  = MED3(m3, m4, (v));  m3 = MED3(m2, m3, (v));          \
        m2  = MED3(m1, m2, (v));  m1 = MED3(m0, m1, (v));          \
        m0  = fminf(m0, (v));                                      \
    }

    float d10g = BIG;
    int k = 1;
    for (;;) {
        stage_scan(k, k >= 2, mnx, mxx, mny, mxy, mnz, mxz,
                   st, sspb, sh.tile, wsum, tid, lane, wv, bodyA);

        // Exact union 11th across the 4 per-wave lists (tile idle now).
        sh.m.ld[wv][lane][0] = d0;  sh.m.ld[wv][lane][1] = d1;
        sh.m.ld[wv][lane][2] = d2;  sh.m.ld[wv][lane][3] = d3;
        sh.m.ld[wv][lane][4] = d4;  sh.m.ld[wv][lane][5] = d5;
        sh.m.ld[wv][lane][6] = d6;  sh.m.ld[wv][lane][7] = d7;
        sh.m.ld[wv][lane][8] = d8;  sh.m.ld[wv][lane][9] = d9;
        sh.m.ld[wv][lane][10] = d10;
        __syncthreads();
        float m0 = d0, m1 = d1, m2 = d2, m3 = d3, m4 = d4, m5 = d5;
        float m6 = d6, m7 = d7, m8 = d8, m9 = d9, m10 = d10;
        {
            const float* q = sh.m.ld[wv ^ 1][lane];
            INS_M(q[0]); INS_M(q[1]); INS_M(q[2]); INS_M(q[3]); INS_M(q[4]);
            INS_M(q[5]); INS_M(q[6]); INS_M(q[7]); INS_M(q[8]); INS_M(q[9]);
            INS_M(q[10]);
        }
        sh.m.ld2[wv >> 1][lane][0] = m0;  sh.m.ld2[wv >> 1][lane][1] = m1;
        sh.m.ld2[wv >> 1][lane][2] = m2;  sh.m.ld2[wv >> 1][lane][3] = m3;
        sh.m.ld2[wv >> 1][lane][4] = m4;  sh.m.ld2[wv >> 1][lane][5] = m5;
        sh.m.ld2[wv >> 1][lane][6] = m6;  sh.m.ld2[wv >> 1][lane][7] = m7;
        sh.m.ld2[wv >> 1][lane][8] = m8;  sh.m.ld2[wv >> 1][lane][9] = m9;
        sh.m.ld2[wv >> 1][lane][10] = m10;
        __syncthreads();
        {
            const float* r = sh.m.ld2[(wv >> 1) ^ 1][lane];
            float g = fminf(m10, r[10]);
            g = fminf(g, fmaxf(m0, r[9])); g = fminf(g, fmaxf(m1, r[8]));
            g = fminf(g, fmaxf(m2, r[7])); g = fminf(g, fmaxf(m3, r[6]));
            g = fminf(g, fmaxf(m4, r[5])); g = fminf(g, fmaxf(m5, r[4]));
            g = fminf(g, fmaxf(m6, r[3])); g = fminf(g, fmaxf(m7, r[2]));
            g = fminf(g, fmaxf(m8, r[1])); g = fminf(g, fmaxf(m9, r[0]));
            d10g = g;
        }
        const float bnd = (float)k * CELL;
        const bool need  = d10g > bnd * bnd;
        const bool cover = (mnx - k <= 0) && (mny - k <= 0) && (mnz - k <= 0) &&
                           (mxx + k >= NC - 1) && (mxy + k >= NC - 1) && (mxz + k >= NC - 1);
        if (cover || !__any(need)) break;
        ++k;
        __syncthreads();                 // ld/ld2 -> tile reuse fence
    }

    // Global argmin (lexicographic over the 4 waves).
    lad[wv][lane] = d0; lai[wv][lane] = i0;
    __syncthreads();                     // also fences ld2 reads before tile reuse
    float gb = BIG; int gi = 0x7fffffff;
#pragma unroll
    for (int w = 0; w < 4; ++w) {
        const float dq = lad[w][lane];
        const int   iq = lai[w][lane];
        const bool take = (dq < gb) || (dq == gb && iq < gi);
        gb = take ? dq : gb;
        gi = take ? iq : gi;
    }
    const int i0g = gi;
    const float4 cpt = sspb[i0g];
    const float ix = cpt.x, iy = cpt.y, iz = cpt.z;
    const float vx = px - ix, vy = py - iy, vz = pz - iz;
    const float d10f = d10g;
    float best = BIG;

    auto bodyB = [&](float sx, float sy, float sz, int t) {
        const float dx = px - sx, dy = py - sy, dz = pz - sz;
        const float nd = fmaf(dx, dx, fmaf(dy, dy, dz * dz));
        const bool adm = (nd <= d10f) && (t != i0g);
        const float ex = sx - ix, ey = sy - iy, ez = sz - iz;
        const float ee = fmaxf(fmaf(ex, ex, fmaf(ey, ey, ez * ez)), 1e-30f);
        const float dt = fmaf(vx, ex, fmaf(vy, ey, vz * ez));
        const float u  = fmaf(-0.5f, ee, dt);
        const float t2 = u * u * __builtin_amdgcn_rcpf(ee);
        best = adm ? fminf(best, t2) : best;
    };

    // Pass B: one full-box scan at the final radius (covers all admissible).
    stage_scan(k, false, mnx, mxx, mny, mxy, mnz, mxz,
               st, sspb, sh.tile, wsum, tid, lane, wv, bodyB);

    lbb[wv][lane] = best;
    __syncthreads();
    if (wv == 0) {
        const float m = fminf(fminf(lbb[0][lane], lbb[1][lane]),
                              fminf(lbb[2][lane], lbb[3][lane]));
        if (valid) out[(size_t)b * NPTS + orig] = m;
    }
}

// ---------------- launch ----------------

extern "C" void kernel_launch(void* const* d_in, const int* in_sizes, int n_in,
                              void* d_out, int out_size, void* d_ws, size_t ws_size,
                              hipStream_t stream) {
    const float* pts  = (const float*)d_in[0];   // (2, 50000, 3)
    const float* spts = (const float*)d_in[1];   // (2, 4000, 3)
    float* out = (float*)d_out;                  // (2, 50000)

    int* W = (int*)d_ws;
    int* sp_cnt   = W;                            // 2*NCL
    int* pt_cnt   = sp_cnt + 2 * NCL;             // 2*NCL
    int* sp_start = pt_cnt + 2 * NCL;             // 2*(NCL+1)
    int* pt_start = sp_start + 2 * (NCL + 1);     // 2*(NCL+1)
    int* sp_cur   = pt_start + 2 * (NCL + 1);     // 2*NCL
    int* pt_cur   = sp_cur + 2 * NCL;             // 2*NCL
    int* perm     = pt_cur + 2 * NCL;             // 2*NPTS
    float4* ssp   = (float4*)(((uintptr_t)(perm + 2 * NPTS) + 15) & ~(uintptr_t)15);

    hipMemsetAsync(W, 0, (size_t)(4 * NCL) * sizeof(int), stream);

    const int npre = (NBATCH * NSP + NBATCH * NPTS + 255) / 256;
    bin_kernel<<<npre, 256, 0, stream>>>(pts, spts, sp_cnt, pt_cnt);
    prefix_kernel<<<4, 1024, 0, stream>>>(sp_cnt, sp_start, sp_cur,
                                          pt_cnt, pt_start, pt_cur);
    scatter_kernel<<<npre, 256, 0, stream>>>(pts, spts, sp_cur, pt_cur, ssp, perm);

    dim3 grid((NPTS + 63) / 64, NBATCH);
    voronoi_main<<<grid, 256, 0, stream>>>(pts, sp_start, ssp, perm, out);
}

// Round 8
// 678.224 us; speedup vs baseline: 2.4352x; 1.1992x over previous
//
#include <hip/hip_runtime.h>
#include <math.h>
#include <stdint.h>

#define NBATCH 2
#define NPTS 50000
#define NSP  4000
#define NC   24                 // cells per axis
#define NCL  (NC * NC * NC)     // 13824 linear cells
#define CELL 0.35f
#define INVC (1.0f / CELL)
#define ORG  4.2f               // grid covers [-4.2, 4.2); 24 * 0.35 = 8.4
#define CAP  1024               // LDS candidate tile (float4)
#define THRESH 72               // box count needed to trust k0 (11 / sphere-box ratio @k=1)
#define BIG  3.4e38f

#define MED3(a,b,c) __builtin_amdgcn_fmed3f((a),(b),(c))

__device__ __forceinline__ int cellc(float x) {
    int c = (int)floorf((x + ORG) * INVC);
    return min(max(c, 0), NC - 1);
}

// ---------------- preprocessing ----------------

__global__ void bin_kernel(const float* __restrict__ pts, const float* __restrict__ spts,
                           int* __restrict__ sp_cnt, int* __restrict__ pt_cnt) {
    const int t = blockIdx.x * 256 + threadIdx.x;
    if (t < NBATCH * NSP) {
        const int b = t / NSP, j = t - b * NSP;
        const float* s = spts + ((size_t)b * NSP + j) * 3;
        const int cc = (cellc(s[2]) * NC + cellc(s[1])) * NC + cellc(s[0]);
        atomicAdd(&sp_cnt[b * NCL + cc], 1);
    } else if (t < NBATCH * NSP + NBATCH * NPTS) {
        const int u = t - NBATCH * NSP;
        const int b = u / NPTS, i = u - b * NPTS;
        const float* p = pts + ((size_t)b * NPTS + i) * 3;
        const int cc = (cellc(p[2]) * NC + cellc(p[1])) * NC + cellc(p[0]);
        atomicAdd(&pt_cnt[b * NCL + cc], 1);
    }
}

__device__ __forceinline__ int satq(const int* s, int x, int y, int z) {
    if (x < 0 || y < 0 || z < 0) return 0;
    x = min(x, NC - 1); y = min(y, NC - 1); z = min(z, NC - 1);
    return s[(z * NC + y) * NC + x];
}
__device__ __forceinline__ int boxcount(const int* s, int x0, int x1, int y0, int y1,
                                        int z0, int z1) {
    return satq(s, x1, y1, z1) - satq(s, x0 - 1, y1, z1) - satq(s, x1, y0 - 1, z1)
         - satq(s, x1, y1, z0 - 1) + satq(s, x0 - 1, y0 - 1, z1)
         + satq(s, x0 - 1, y1, z0 - 1) + satq(s, x1, y0 - 1, z0 - 1)
         - satq(s, x0 - 1, y0 - 1, z0 - 1);
}

// 6 blocks: 0,1 sp-prefix; 2,3 pt-prefix; 4,5 SAT + per-cell k0 table.
__global__ void prefix_sat_kernel(int* __restrict__ sp_cnt, int* __restrict__ sp_start,
                                  int* __restrict__ sp_cur,
                                  int* __restrict__ pt_cnt, int* __restrict__ pt_start,
                                  int* __restrict__ pt_cur, int* __restrict__ k0g) {
    __shared__ union {
        struct { int wsum[16], wpre[16], stot; } p;
        int sat[NCL];
    } sh;
    const int role = blockIdx.x;
    if (role < 4) {
        const bool ispt = role >= 2;
        const int b = role & 1;
        int* cnt = (ispt ? pt_cnt : sp_cnt) + b * NCL;
        int* st  = (ispt ? pt_start : sp_start) + b * (NCL + 1);
        int* cu  = (ispt ? pt_cur : sp_cur) + b * NCL;
        const int lane = threadIdx.x & 63, wid = threadIdx.x >> 6;
        int carry = 0;
        for (int base = 0; base < NCL; base += 1024) {
            const int i = base + (int)threadIdx.x;
            const int v = (i < NCL) ? cnt[i] : 0;
            int s = v;
#pragma unroll
            for (int o = 1; o < 64; o <<= 1) { int t2 = __shfl_up(s, o); if (lane >= o) s += t2; }
            if (lane == 63) sh.p.wsum[wid] = s;
            __syncthreads();
            if (threadIdx.x == 0) {
                int a = 0;
                for (int w = 0; w < 16; ++w) { sh.p.wpre[w] = a; a += sh.p.wsum[w]; }
                sh.p.stot = a;
            }
            __syncthreads();
            const int exc = carry + sh.p.wpre[wid] + s - v;
            if (i < NCL) { st[i] = exc; cu[i] = exc; }
            carry += sh.p.stot;
            __syncthreads();
        }
        if (threadIdx.x == 0) st[NCL] = carry;
    } else {
        const int b = role - 4;
        for (int i = threadIdx.x; i < NCL; i += 1024) sh.sat[i] = sp_cnt[b * NCL + i];
        __syncthreads();
        if (threadIdx.x < NC * NC) {            // x-scan, thread owns (y,z)
            const int z = threadIdx.x / NC, y = threadIdx.x % NC;
            const int base = (z * NC + y) * NC;
            int acc = 0;
            for (int x = 0; x < NC; ++x) { acc += sh.sat[base + x]; sh.sat[base + x] = acc; }
        }
        __syncthreads();
        if (threadIdx.x < NC * NC) {            // y-scan, thread owns (x,z)
            const int z = threadIdx.x / NC, x = threadIdx.x % NC;
            int acc = 0;
            for (int y = 0; y < NC; ++y) {
                const int idx = (z * NC + y) * NC + x;
                acc += sh.sat[idx]; sh.sat[idx] = acc;
            }
        }
        __syncthreads();
        if (threadIdx.x < NC * NC) {            // z-scan, thread owns (x,y)
            const int y = threadIdx.x / NC, x = threadIdx.x % NC;
            int acc = 0;
            for (int z = 0; z < NC; ++z) {
                const int idx = (z * NC + y) * NC + x;
                acc += sh.sat[idx]; sh.sat[idx] = acc;
            }
        }
        __syncthreads();
        for (int c = threadIdx.x; c < NCL; c += 1024) {
            const int z = c / (NC * NC), r2 = c % (NC * NC), y = r2 / NC, x = r2 % NC;
            int k = 1;
            for (; k < NC; ++k) {
                if (boxcount(sh.sat, x - k, x + k, y - k, y + k, z - k, z + k) >= THRESH)
                    break;
                if (x - k <= 0 && y - k <= 0 && z - k <= 0 &&
                    x + k >= NC - 1 && y + k >= NC - 1 && z + k >= NC - 1)
                    break;                       // box covers the grid
            }
            k0g[b * NCL + c] = k;
        }
    }
}

__global__ void scatter_kernel(const float* __restrict__ pts, const float* __restrict__ spts,
                               int* __restrict__ sp_cur, int* __restrict__ pt_cur,
                               float4* __restrict__ ssp, int* __restrict__ perm) {
    const int t = blockIdx.x * 256 + threadIdx.x;
    if (t < NBATCH * NSP) {
        const int b = t / NSP, j = t - b * NSP;
        const float* s = spts + ((size_t)b * NSP + j) * 3;
        const float x = s[0], y = s[1], z = s[2];
        const int cc = (cellc(z) * NC + cellc(y)) * NC + cellc(x);
        const int pos = atomicAdd(&sp_cur[b * NCL + cc], 1);
        ssp[b * NSP + pos] = make_float4(x, y, z, 0.f);
    } else if (t < NBATCH * NSP + NBATCH * NPTS) {
        const int u = t - NBATCH * NSP;
        const int b = u / NPTS, i = u - b * NPTS;
        const float* p = pts + ((size_t)b * NPTS + i) * 3;
        const int cc = (cellc(p[2]) * NC + cellc(p[1])) * NC + cellc(p[0]);
        const int pos = atomicAdd(&pt_cur[b * NCL + cc], 1);
        perm[b * NPTS + pos] = i;
    }
}

// ---------------- main kernel ----------------

// Gather all cells of box_k (shell=false) or box_k \ box_{k-1} (shell=true)
// into the LDS tile (windowed, exact), scanning windows with `body`.
template <class F>
__device__ __forceinline__ void stage_scan(
    int k, bool shell,
    int mnx, int mxx, int mny, int mxy, int mnz, int mxz,
    const int* __restrict__ st, const float4* __restrict__ sspb,
    float4* __restrict__ tile, int* __restrict__ wsum,
    int tid, int lane, int wv, int& fill_out, bool& flushed, F&& body)
{
    const int xlo = mnx - k, ylo = mny - k, zlo = mnz - k;
    const int nx = mxx - mnx + 1 + 2 * k;
    const int ny = mxy - mny + 1 + 2 * k;
    const int nz = mxz - mnz + 1 + 2 * k;
    const int nxy = nx * ny;
    const int ncells = nxy * nz;
    int fill = 0;                       // uniform across threads
    for (int base = 0; base < ncells; base += 256) {
        const int idx = base + tid;
        int cnt = 0, src = 0;
        if (idx < ncells) {
            const int cz = idx / nxy;
            const int r  = idx - cz * nxy;
            const int cy = r / nx;
            const int cx = r - cy * nx;
            const bool skip = shell && cx >= 1 && cx <= nx - 2 &&
                              cy >= 1 && cy <= ny - 2 && cz >= 1 && cz <= nz - 2;
            const int ax = xlo + cx, ay = ylo + cy, az = zlo + cz;
            if (!skip && (unsigned)ax < NC && (unsigned)ay < NC && (unsigned)az < NC) {
                const int c = (az * NC + ay) * NC + ax;
                src = st[c];
                cnt = st[c + 1] - src;
            }
        }
        int s = cnt;
#pragma unroll
        for (int o = 1; o < 64; o <<= 1) { const int t2 = __shfl_up(s, o); if (lane >= o) s += t2; }
        if (lane == 63) wsum[wv] = s;
        __syncthreads();
        const int t0 = wsum[0], t1 = wsum[1], t2w = wsum[2], t3 = wsum[3];
        int wpre = 0;
        if (wv > 0) wpre += t0;
        if (wv > 1) wpre += t1;
        if (wv > 2) wpre += t2w;
        const int total = t0 + t1 + t2w + t3;
        __syncthreads();

        int dst  = fill + wpre + (s - cnt);
        int rem  = cnt;
        int srcp = src;
        int newfill = fill + total;     // uniform
        while (newfill > CAP) {
            flushed = true;
            while (rem > 0 && dst < CAP) {
                const float4 v = sspb[srcp];
                tile[dst] = make_float4(v.x, v.y, v.z, __int_as_float(srcp));
                ++dst; ++srcp; --rem;
            }
            __syncthreads();
            {
                const int lo = (CAP * wv) >> 2, hi = (CAP * (wv + 1)) >> 2;
                for (int i = lo; i < hi; ++i) {
                    const float4 sv = tile[i];
                    body(sv.x, sv.y, sv.z, __float_as_int(sv.w));
                }
            }
            __syncthreads();
            dst -= CAP;
            newfill -= CAP;
        }
        while (rem > 0) {
            const float4 v = sspb[srcp];
            tile[dst] = make_float4(v.x, v.y, v.z, __int_as_float(srcp));
            ++dst; ++srcp; --rem;
        }
        fill = newfill;
    }
    __syncthreads();
    if (fill > 0) {
        const int lo = (fill * wv) >> 2, hi = (fill * (wv + 1)) >> 2;
        for (int i = lo; i < hi; ++i) {
            const float4 sv = tile[i];
            body(sv.x, sv.y, sv.z, __float_as_int(sv.w));
        }
    }
    __syncthreads();
    fill_out = fill;
}

__global__ __launch_bounds__(256, 5) void voronoi_main(
    const float* __restrict__ pts,
    const int* __restrict__ sp_start,
    const float4* __restrict__ ssp,
    const int* __restrict__ perm,
    const int* __restrict__ k0g,
    float* __restrict__ out)
{
    __shared__ float4 tile[CAP];                 // 16 KB gather tile (persists to pass B)
    __shared__ float  ld[4][64][13];             // per-wave top-11 lists (pad 13)
    __shared__ float  lad[4][64];
    __shared__ union { int i[4][64]; float f[4][64]; } lx;   // lai then lbb
    __shared__ int    wsum[4];

    const int tid  = threadIdx.x;
    const int lane = tid & 63;
    const int wv   = __builtin_amdgcn_readfirstlane(tid >> 6);
    const int b    = blockIdx.y;

    int sidx = blockIdx.x * 64 + lane;
    const bool valid = (sidx < NPTS);
    sidx = min(sidx, NPTS - 1);
    const int orig = perm[b * NPTS + sidx];
    const float* pp = pts + ((size_t)b * NPTS + orig) * 3;
    const float px = pp[0], py = pp[1], pz = pp[2];
    const int icx = cellc(px), icy = cellc(py), icz = cellc(pz);

    // Block jump-start k: max over member cells' k0.
    int kk = k0g[b * NCL + (icz * NC + icy) * NC + icx];
#pragma unroll
    for (int o = 1; o < 64; o <<= 1) kk = max(kk, __shfl_xor(kk, o));
    const int k_start = __builtin_amdgcn_readfirstlane(kk);

    // Group bbox (identical across the 4 waves).
    int mnx = icx, mxx = icx, mny = icy, mxy = icy, mnz = icz, mxz = icz;
#pragma unroll
    for (int o = 1; o < 64; o <<= 1) {
        mnx = min(mnx, __shfl_xor(mnx, o)); mxx = max(mxx, __shfl_xor(mxx, o));
        mny = min(mny, __shfl_xor(mny, o)); mxy = max(mxy, __shfl_xor(mxy, o));
        mnz = min(mnz, __shfl_xor(mnz, o)); mxz = max(mxz, __shfl_xor(mxz, o));
    }
    mnx = __builtin_amdgcn_readfirstlane(mnx); mxx = __builtin_amdgcn_readfirstlane(mxx);
    mny = __builtin_amdgcn_readfirstlane(mny); mxy = __builtin_amdgcn_readfirstlane(mxy);
    mnz = __builtin_amdgcn_readfirstlane(mnz); mxz = __builtin_amdgcn_readfirstlane(mxz);

    const int* st = sp_start + b * (NCL + 1);
    const float4* sspb = ssp + (size_t)b * NSP;

    float d0 = BIG, d1 = BIG, d2 = BIG, d3 = BIG, d4 = BIG, d5 = BIG;
    float d6 = BIG, d7 = BIG, d8 = BIG, d9 = BIG, d10 = BIG;
    int i0 = 0;

    auto bodyA = [&](float sx, float sy, float sz, int t) {
        const float dx = px - sx, dy = py - sy, dz = pz - sz;
        const float nd = fmaf(dx, dx, fmaf(dy, dy, dz * dz));
        d10 = MED3(d9, d10, nd); d9 = MED3(d8, d9, nd); d8 = MED3(d7, d8, nd);
        d7  = MED3(d6, d7,  nd); d6 = MED3(d5, d6, nd); d5 = MED3(d4, d5, nd);
        d4  = MED3(d3, d4,  nd); d3 = MED3(d2, d3, nd); d2 = MED3(d1, d2, nd);
        d1  = MED3(d0, d1,  nd);
        i0 = (nd < d0) ? t : i0;
        d0 = fminf(d0, nd);
    };

#define INS_M(v) {                                                 \
        m10 = MED3(m9, m10, (v)); m9 = MED3(m8, m9, (v));          \
        m8  = MED3(m7, m8, (v));  m7 = MED3(m6, m7, (v));          \
        m6  = MED3(m5, m6, (v));  m5 = MED3(m4, m5, (v));          \
        m4  = MED3(m3, m4, (v));  m3 = MED3(m2, m3, (v));          \
        m2  = MED3(m1, m2, (v));  m1 = MED3(m0, m1, (v));          \
        m0  = fminf(m0, (v));                                      \
    }

    int k = k_start;
    int fill = 0;
    bool flushed = false;
    stage_scan(k, false, mnx, mxx, mny, mxy, mnz, mxz,
               st, sspb, tile, wsum, tid, lane, wv, fill, flushed, bodyA);

    float d10g = BIG;
    for (;;) {
        // Exact union 11th across 4 disjoint per-wave lists (own lists preserved).
        ld[wv][lane][0] = d0;  ld[wv][lane][1] = d1;  ld[wv][lane][2] = d2;
        ld[wv][lane][3] = d3;  ld[wv][lane][4] = d4;  ld[wv][lane][5] = d5;
        ld[wv][lane][6] = d6;  ld[wv][lane][7] = d7;  ld[wv][lane][8] = d8;
        ld[wv][lane][9] = d9;  ld[wv][lane][10] = d10;
        __syncthreads();
        float m0 = d0, m1 = d1, m2 = d2, m3 = d3, m4 = d4, m5 = d5;
        float m6 = d6, m7 = d7, m8 = d8, m9 = d9, m10 = d10;
#pragma unroll
        for (int w = 0; w < 4; ++w) {
            if (w == wv) continue;               // wave-uniform
            const float* q = ld[w][lane];
            INS_M(q[0]); INS_M(q[1]); INS_M(q[2]); INS_M(q[3]); INS_M(q[4]);
            INS_M(q[5]); INS_M(q[6]); INS_M(q[7]); INS_M(q[8]); INS_M(q[9]);
            INS_M(q[10]);
        }
        d10g = m10;

        const float bnd = (float)k * CELL;
        const bool need  = d10g > bnd * bnd;
        const bool cover = (mnx - k <= 0) && (mny - k <= 0) && (mnz - k <= 0) &&
                           (mxx + k >= NC - 1) && (mxy + k >= NC - 1) && (mxz + k >= NC - 1);
        if (cover || !__any(need)) break;
        ++k;
        __syncthreads();                         // ld reads done before next writes
        stage_scan(k, true, mnx, mxx, mny, mxy, mnz, mxz,
                   st, sspb, tile, wsum, tid, lane, wv, fill, flushed, bodyA);
    }

    // Global argmin (lexicographic over the 4 waves).
    lad[wv][lane] = d0; lx.i[wv][lane] = i0;
    __syncthreads();
    float gb = BIG; int gi = 0x7fffffff;
#pragma unroll
    for (int w = 0; w < 4; ++w) {
        const float dq = lad[w][lane];
        const int   iq = lx.i[w][lane];
        const bool take = (dq < gb) || (dq == gb && iq < gi);
        gb = take ? dq : gb;
        gi = take ? iq : gi;
    }
    const int i0g = gi;
    const float4 cpt = sspb[i0g];
    const float ix = cpt.x, iy = cpt.y, iz = cpt.z;
    const float vx = px - ix, vy = py - iy, vz = pz - iz;
    const float d10f = d10g;
    float best = BIG;

    auto bodyB = [&](float sx, float sy, float sz, int t) {
        const float dx = px - sx, dy = py - sy, dz = pz - sz;
        const float nd = fmaf(dx, dx, fmaf(dy, dy, dz * dz));
        const bool adm = (nd <= d10f) && (t != i0g);
        const float ex = sx - ix, ey = sy - iy, ez = sz - iz;
        const float ee = fmaxf(fmaf(ex, ex, fmaf(ey, ey, ez * ez)), 1e-30f);
        const float dt = fmaf(vx, ex, fmaf(vy, ey, vz * ez));
        const float u  = fmaf(-0.5f, ee, dt);
        const float t2 = u * u * __builtin_amdgcn_rcpf(ee);
        best = adm ? fminf(best, t2) : best;
    };

    // Pass B: reuse resident tile when it still holds the full final box.
    const bool reuse = (!flushed) && (k == k_start);     // block-uniform
    if (reuse) {
        const int lo = (fill * wv) >> 2, hi = (fill * (wv + 1)) >> 2;
        for (int i = lo; i < hi; ++i) {
            const float4 sv = tile[i];
            bodyB(sv.x, sv.y, sv.z, __float_as_int(sv.w));
        }
    } else {
        stage_scan(k, false, mnx, mxx, mny, mxy, mnz, mxz,
                   st, sspb, tile, wsum, tid, lane, wv, fill, flushed, bodyB);
    }

    __syncthreads();                             // lx.i reads done before lx.f writes
    lx.f[wv][lane] = best;
    __syncthreads();
    if (wv == 0) {
        const float m = fminf(fminf(lx.f[0][lane], lx.f[1][lane]),
                              fminf(lx.f[2][lane], lx.f[3][lane]));
        if (valid) out[(size_t)b * NPTS + orig] = m;
    }
}

// ---------------- launch ----------------

extern "C" void kernel_launch(void* const* d_in, const int* in_sizes, int n_in,
                              void* d_out, int out_size, void* d_ws, size_t ws_size,
                              hipStream_t stream) {
    const float* pts  = (const float*)d_in[0];   // (2, 50000, 3)
    const float* spts = (const float*)d_in[1];   // (2, 4000, 3)
    float* out = (float*)d_out;                  // (2, 50000)

    int* W = (int*)d_ws;
    int* sp_cnt   = W;                            // 2*NCL
    int* pt_cnt   = sp_cnt + 2 * NCL;             // 2*NCL
    int* sp_start = pt_cnt + 2 * NCL;             // 2*(NCL+1)
    int* pt_start = sp_start + 2 * (NCL + 1);     // 2*(NCL+1)
    int* sp_cur   = pt_start + 2 * (NCL + 1);     // 2*NCL
    int* pt_cur   = sp_cur + 2 * NCL;             // 2*NCL
    int* k0g      = pt_cur + 2 * NCL;             // 2*NCL
    int* perm     = k0g + 2 * NCL;                // 2*NPTS
    float4* ssp   = (float4*)(((uintptr_t)(perm + 2 * NPTS) + 15) & ~(uintptr_t)15);

    hipMemsetAsync(W, 0, (size_t)(4 * NCL) * sizeof(int), stream);

    const int npre = (NBATCH * NSP + NBATCH * NPTS + 255) / 256;
    bin_kernel<<<npre, 256, 0, stream>>>(pts, spts, sp_cnt, pt_cnt);
    prefix_sat_kernel<<<6, 1024, 0, stream>>>(sp_cnt, sp_start, sp_cur,
                                              pt_cnt, pt_start, pt_cur, k0g);
    scatter_kernel<<<npre, 256, 0, stream>>>(pts, spts, sp_cur, pt_cur, ssp, perm);

    dim3 grid((NPTS + 63) / 64, NBATCH);
    voronoi_main<<<grid, 256, 0, stream>>>(pts, sp_start, ssp, perm, k0g, out);
}